// Round 12
// baseline (128.931 us; speedup 1.0000x reference)
//
#include <hip/hip_runtime.h>
#include <hip/hip_bf16.h>

typedef __bf16 bf16x8 __attribute__((ext_vector_type(8)));
typedef float f32x16 __attribute__((ext_vector_type(16)));

constexpr int NROW = 8192;
constexpr int DCOL = 256;
constexpr int BM = 128;
constexpr int BK = 64;
constexpr int NKT = DCOL / BK;             // 4
constexpr int NT = NROW / BM;              // 64
constexpr int NTILES = NT * (NT + 1) / 2;  // 2080 (divisible by 8)
constexpr float MARGIN = 0.3f;

// async global->LDS, 16B per lane; LDS dest is wave-uniform base (HW adds lane*16)
__device__ inline void gload16(const unsigned short* g, unsigned short* l) {
    __builtin_amdgcn_global_load_lds(
        (const __attribute__((address_space(1))) void*)g,
        (__attribute__((address_space(3))) void*)l, 16, 0, 0);
}

// ---------------- normalize rows -> bf16 ----------------
__global__ __launch_bounds__(256) void normalize_kernel(const float* __restrict__ hidden,
                                                        unsigned short* __restrict__ xn) {
    int wid = threadIdx.x >> 6, lane = threadIdx.x & 63;
    int row = (blockIdx.x << 2) + wid;
    const float4* src = reinterpret_cast<const float4*>(hidden + (size_t)row * DCOL);
    float4 v = src[lane];
    float ss = v.x * v.x + v.y * v.y + v.z * v.z + v.w * v.w;
    #pragma unroll
    for (int off = 32; off; off >>= 1) ss += __shfl_down(ss, off);
    ss = __shfl(ss, 0);
    float inv = 1.0f / fmaxf(sqrtf(ss), 1e-8f);
    __hip_bfloat16 b0 = __float2bfloat16(v.x * inv);
    __hip_bfloat16 b1 = __float2bfloat16(v.y * inv);
    __hip_bfloat16 b2 = __float2bfloat16(v.z * inv);
    __hip_bfloat16 b3 = __float2bfloat16(v.w * inv);
    ushort4 o;
    o.x = *reinterpret_cast<unsigned short*>(&b0);
    o.y = *reinterpret_cast<unsigned short*>(&b1);
    o.z = *reinterpret_cast<unsigned short*>(&b2);
    o.w = *reinterpret_cast<unsigned short*>(&b3);
    reinterpret_cast<ushort4*>(xn + (size_t)row * DCOL)[lane] = o;
}

// ---------------- 128x128-tile, 4-wave, dbuf-prefetch MFMA Gram + fused pair loss ----------------
// EXACT r8 production config (the best inferred: ~17us/rep). REPS=1: real kernel.
// REPS=4: diagnostic probe of the SAME config, visible in rocprof top-5 (>42us fill floor),
// giving a direct per-dispatch measurement instead of end-to-end subtraction.
template<int REPS>
__global__ __launch_bounds__(256) void pairloss_kernel(const unsigned short* __restrict__ xn,
                                                       const int* __restrict__ labels,
                                                       float* __restrict__ partials) {
    __shared__ unsigned short As[2][BM * BK];   // 2 x 16KB
    __shared__ unsigned short Bs[2][BM * BK];   // 2 x 16KB
    __shared__ int lblA[BM], lblB[BM];
    __shared__ float wsum[4];

    // XCD-aware bijective swizzle
    int bid = (int)(blockIdx.x & 7) * (NTILES / 8) + (int)(blockIdx.x >> 3);
    int bi = 0, rem = bid;
    while (rem >= NT - bi) { rem -= NT - bi; ++bi; }
    int bj = bi + rem;

    int tid = threadIdx.x;
    int wid = tid >> 6, lane = tid & 63;
    int wr = wid >> 1, wc = wid & 1;            // 2x2 waves, wave tile 64x64
    int brow = bi * BM, bcol = bj * BM;

    if (tid < BM) lblA[tid] = labels[brow + tid];
    else          lblB[tid - BM] = labels[bcol + tid - BM];

    f32x16 acc[2][2] = {};                      // 2x2 tiles of 32x32 per wave

    int srow = lane >> 3;
    int schunk = (lane & 7) ^ srow;             // pre-swizzled source chunk (r&7 == srow)
    const unsigned short* gA0 = xn + (size_t)brow * DCOL;
    const unsigned short* gB0 = xn + (size_t)bcol * DCOL;
    int lo = lane & 31, hi = lane >> 5;

    auto stage = [&](int t, int b) {            // 8 VMEM instr/thread per K-tile
        #pragma unroll
        for (int q = 0; q < 4; ++q) {
            int rg = (wid * 4 + q) * 8;         // wave-uniform 8-row group
            int goff = (rg + srow) * DCOL + t * BK + schunk * 8;
            gload16(gA0 + goff, &As[b][rg * BK]);
            gload16(gB0 + goff, &Bs[b][rg * BK]);
        }
    };
    auto compute = [&](int b) {
        #pragma unroll
        for (int kk = 0; kk < 4; ++kk) {        // K16 sub-steps of BK=64 (compile-time kk)
            bf16x8 af[2], bfr[2];
            int cb = kk * 2 + hi;               // 16B k-chunk 0..7
            #pragma unroll
            for (int m = 0; m < 2; ++m) {
                int r = wr * 64 + m * 32 + lo;  // r&7 == lane&7
                af[m] = *reinterpret_cast<const bf16x8*>(&As[b][r * BK + ((cb ^ (r & 7)) << 3)]);
            }
            #pragma unroll
            for (int n = 0; n < 2; ++n) {
                int r = wc * 64 + n * 32 + lo;
                bfr[n] = *reinterpret_cast<const bf16x8*>(&Bs[b][r * BK + ((cb ^ (r & 7)) << 3)]);
            }
            __builtin_amdgcn_s_setprio(1);
            #pragma unroll
            for (int m = 0; m < 2; ++m)
                #pragma unroll
                for (int n = 0; n < 2; ++n)
                    acc[m][n] = __builtin_amdgcn_mfma_f32_32x32x16_bf16(af[m], bfr[n], acc[m][n], 0, 0, 0);
            __builtin_amdgcn_s_setprio(0);
        }
    };

    for (int rep = 0; rep < REPS; ++rep) {
        stage(0, 0);                            // prologue (only exposed wait per block)
        for (int t = 0; t < NKT; ++t) {
            int c = t & 1;
            asm volatile("s_waitcnt vmcnt(0)" ::: "memory");  // tile t's loads are 1 compute old
            __builtin_amdgcn_s_barrier();       // buf[c] valid for all; buf[c^1] readers done
            if (t + 1 < NKT) stage(t + 1, c ^ 1);  // prefetch flies under compute(t)
            compute(c);
        }
    }

    // epilogue: per-pair loss, strict upper triangle
    // 32x32 C/D: col = lane&31, row = (reg&3) + 8*(reg>>2) + 4*(lane>>5)
    float local = 0.0f;
    #pragma unroll
    for (int m = 0; m < 2; ++m) {
        #pragma unroll
        for (int n = 0; n < 2; ++n) {
            #pragma unroll
            for (int g = 0; g < 16; ++g) {
                int crow = (g & 3) + 8 * (g >> 2) + 4 * hi;
                int il = wr * 64 + m * 32 + crow;
                int jl = wc * 64 + n * 32 + lo;
                int gi = brow + il, gj = bcol + jl;
                float sim = acc[m][n][g];
                float v = (lblA[il] == lblB[jl]) ? (1.0f - sim) : fmaxf(sim - MARGIN, 0.0f);
                local += (gi < gj) ? v : 0.0f;
            }
        }
    }
    #pragma unroll
    for (int off = 32; off; off >>= 1) local += __shfl_down(local, off);
    if (lane == 0) wsum[wid] = local;
    __syncthreads();
    if (tid == 0) partials[bid] = wsum[0] + wsum[1] + wsum[2] + wsum[3];
}

// ---------------- reduce partials -> loss ----------------
__global__ __launch_bounds__(512) void finalize_kernel(const float* __restrict__ partials,
                                                       float* __restrict__ out) {
    __shared__ float wsum[8];
    int tid = threadIdx.x, wid = tid >> 6, lane = tid & 63;
    float s = 0.0f;
    for (int i = tid; i < NTILES; i += 512) s += partials[i];
    #pragma unroll
    for (int off = 32; off; off >>= 1) s += __shfl_down(s, off);
    if (lane == 0) wsum[wid] = s;
    __syncthreads();
    if (tid == 0) {
        float total = 0.0f;
        #pragma unroll
        for (int w = 0; w < 8; ++w) total += wsum[w];
        out[0] = total * (1.0f / 33550336.0f);  // / (N*(N-1)/2)
    }
}

extern "C" void kernel_launch(void* const* d_in, const int* in_sizes, int n_in,
                              void* d_out, int out_size, void* d_ws, size_t ws_size,
                              hipStream_t stream) {
    const float* hidden = (const float*)d_in[0];
    const int* labels = (const int*)d_in[1];
    float* out = (float*)d_out;

    unsigned short* xn = (unsigned short*)d_ws;                              // 4 MB
    float* partials = (float*)((char*)d_ws + (size_t)NROW * DCOL * 2);       // 2080 floats
    float* scratch  = partials + NTILES;                                     // probe output

    normalize_kernel<<<NROW / 4, 256, 0, stream>>>(hidden, xn);
    pairloss_kernel<1><<<NTILES, 256, 0, stream>>>(xn, labels, partials);
    finalize_kernel<<<1, 512, 0, stream>>>(partials, out);
    // diagnostic probe (output unused): SAME config x4 reps -> direct per-dispatch counters
    pairloss_kernel<4><<<NTILES, 256, 0, stream>>>(xn, labels, scratch);
}

// Round 13
// 40.816 us; speedup vs baseline: 3.1588x; 3.1588x over previous
//
#include <hip/hip_runtime.h>
#include <hip/hip_bf16.h>
#include <hip/hip_fp8.h>

typedef float f32x16 __attribute__((ext_vector_type(16)));

constexpr int NROW = 8192;
constexpr int DCOL = 256;                  // row length in elements (= bytes in fp8)
constexpr int BM = 128;
constexpr int BKB = 128;                   // K-slab in BYTES (=128 fp8 elems): full 8-chunk swizzle period
constexpr int NKT = DCOL / BKB;            // 2 K-tiles
constexpr int NT = NROW / BM;              // 64
constexpr int NTILES = NT * (NT + 1) / 2;  // 2080 (divisible by 8)
constexpr float MARGIN = 0.3f;

// async global->LDS, 16B per lane; LDS dest is wave-uniform base (HW adds lane*16)
__device__ inline void gload16(const unsigned char* g, unsigned char* l) {
    __builtin_amdgcn_global_load_lds(
        (const __attribute__((address_space(1))) void*)g,
        (__attribute__((address_space(3))) void*)l, 16, 0, 0);
}

// ---------------- normalize rows -> fp8 e4m3 ----------------
__global__ __launch_bounds__(256) void normalize_kernel(const float* __restrict__ hidden,
                                                        unsigned char* __restrict__ xn) {
    int wid = threadIdx.x >> 6, lane = threadIdx.x & 63;
    int row = (blockIdx.x << 2) + wid;
    const float4* src = reinterpret_cast<const float4*>(hidden + (size_t)row * DCOL);
    float4 v = src[lane];
    float ss = v.x * v.x + v.y * v.y + v.z * v.z + v.w * v.w;
    #pragma unroll
    for (int off = 32; off; off >>= 1) ss += __shfl_down(ss, off);
    ss = __shfl(ss, 0);
    float inv = 1.0f / fmaxf(sqrtf(ss), 1e-8f);
    __hip_fp8_e4m3 q0(v.x * inv), q1(v.y * inv), q2(v.z * inv), q3(v.w * inv);
    uchar4 o;
    o.x = *reinterpret_cast<unsigned char*>(&q0);
    o.y = *reinterpret_cast<unsigned char*>(&q1);
    o.z = *reinterpret_cast<unsigned char*>(&q2);
    o.w = *reinterpret_cast<unsigned char*>(&q3);
    reinterpret_cast<uchar4*>(xn + (size_t)row * DCOL)[lane] = o;
}

// ---------------- 128x128-tile, 4-wave, dbuf-prefetch fp8 MFMA Gram + fused pair loss --------
// r12 skeleton, fp8 data: staged bytes halved (133MB), NKT=2, 32 MFMA per K-tile per wave
// (2067 cyc compute window >= L2 load latency -> distance-1 prefetch finally covers),
// ds_read_b64 fragments (half the LDS dependency chain that capped compute at 52%).
__global__ __launch_bounds__(256) void pairloss_kernel(const unsigned char* __restrict__ xn,
                                                       const int* __restrict__ labels,
                                                       float* __restrict__ partials) {
    __shared__ unsigned char As[2][BM * BKB];   // 2 x 16KB
    __shared__ unsigned char Bs[2][BM * BKB];   // 2 x 16KB
    __shared__ int lblA[BM], lblB[BM];
    __shared__ float wsum[4];

    // XCD-aware bijective swizzle
    int bid = (int)(blockIdx.x & 7) * (NTILES / 8) + (int)(blockIdx.x >> 3);
    int bi = 0, rem = bid;
    while (rem >= NT - bi) { rem -= NT - bi; ++bi; }
    int bj = bi + rem;

    int tid = threadIdx.x;
    int wid = tid >> 6, lane = tid & 63;
    int wr = wid >> 1, wc = wid & 1;            // 2x2 waves, wave tile 64x64
    int brow = bi * BM, bcol = bj * BM;

    if (tid < BM) lblA[tid] = labels[brow + tid];
    else          lblB[tid - BM] = labels[bcol + tid - BM];

    f32x16 acc[2][2] = {};                      // 2x2 tiles of 32x32 per wave

    int srow = lane >> 3;                       // 0..7: row within 8-row group
    int schunk = (lane & 7) ^ srow;             // pre-swizzled 16B source chunk (r&7 == srow)
    const unsigned char* gA0 = xn + (size_t)brow * DCOL;
    const unsigned char* gB0 = xn + (size_t)bcol * DCOL;
    int lo = lane & 31, hi = lane >> 5;

    auto stage = [&](int t, int b) {            // 8 VMEM instr/thread per K-tile
        #pragma unroll
        for (int q = 0; q < 4; ++q) {
            int rg = (wid * 4 + q) * 8;         // wave-uniform 8-row group (16 groups/panel)
            int goff = (rg + srow) * DCOL + t * BKB + schunk * 16;
            gload16(gA0 + goff, &As[b][rg * BKB]);   // 8 rows x 128B, linear dest
            gload16(gB0 + goff, &Bs[b][rg * BKB]);
        }
    };
    auto compute = [&](int b) {
        #pragma unroll
        for (int kk = 0; kk < 8; ++kk) {        // K16 sub-steps of BKB=128
            long af[2], bfr[2];                 // 8 fp8 = 2 VGPRs each
            #pragma unroll
            for (int m = 0; m < 2; ++m) {
                int r = wr * 64 + m * 32 + lo;  // r&7 == lane&7
                af[m] = *reinterpret_cast<const long*>(
                    &As[b][r * BKB + ((kk ^ (r & 7)) << 4) + hi * 8]);
            }
            #pragma unroll
            for (int n = 0; n < 2; ++n) {
                int r = wc * 64 + n * 32 + lo;
                bfr[n] = *reinterpret_cast<const long*>(
                    &Bs[b][r * BKB + ((kk ^ (r & 7)) << 4) + hi * 8]);
            }
            __builtin_amdgcn_s_setprio(1);
            #pragma unroll
            for (int m = 0; m < 2; ++m)
                #pragma unroll
                for (int n = 0; n < 2; ++n)
                    acc[m][n] = __builtin_amdgcn_mfma_f32_32x32x16_fp8_fp8(af[m], bfr[n], acc[m][n], 0, 0, 0);
            __builtin_amdgcn_s_setprio(0);
        }
    };

    stage(0, 0);                                // prologue (only exposed wait per block)
    for (int t = 0; t < NKT; ++t) {
        int c = t & 1;
        asm volatile("s_waitcnt vmcnt(0)" ::: "memory");  // tile t's loads are 1 compute old
        __builtin_amdgcn_s_barrier();           // buf[c] valid for all; buf[c^1] readers done
        if (t + 1 < NKT) stage(t + 1, c ^ 1);   // prefetch flies under compute(t)
        compute(c);
    }

    // epilogue: per-pair loss, strict upper triangle
    // 32x32 C/D: col = lane&31, row = (reg&3) + 8*(reg>>2) + 4*(lane>>5)  (dtype-independent)
    float local = 0.0f;
    #pragma unroll
    for (int m = 0; m < 2; ++m) {
        #pragma unroll
        for (int n = 0; n < 2; ++n) {
            #pragma unroll
            for (int g = 0; g < 16; ++g) {
                int crow = (g & 3) + 8 * (g >> 2) + 4 * hi;
                int il = wr * 64 + m * 32 + crow;
                int jl = wc * 64 + n * 32 + lo;
                int gi = brow + il, gj = bcol + jl;
                float sim = acc[m][n][g];
                float v = (lblA[il] == lblB[jl]) ? (1.0f - sim) : fmaxf(sim - MARGIN, 0.0f);
                local += (gi < gj) ? v : 0.0f;
            }
        }
    }
    #pragma unroll
    for (int off = 32; off; off >>= 1) local += __shfl_down(local, off);
    if (lane == 0) wsum[wid] = local;
    __syncthreads();
    if (tid == 0) partials[bid] = wsum[0] + wsum[1] + wsum[2] + wsum[3];
}

// ---------------- reduce partials -> loss ----------------
__global__ __launch_bounds__(512) void finalize_kernel(const float* __restrict__ partials,
                                                       float* __restrict__ out) {
    __shared__ float wsum[8];
    int tid = threadIdx.x, wid = tid >> 6, lane = tid & 63;
    float s = 0.0f;
    for (int i = tid; i < NTILES; i += 512) s += partials[i];
    #pragma unroll
    for (int off = 32; off; off >>= 1) s += __shfl_down(s, off);
    if (lane == 0) wsum[wid] = s;
    __syncthreads();
    if (tid == 0) {
        float total = 0.0f;
        #pragma unroll
        for (int w = 0; w < 8; ++w) total += wsum[w];
        out[0] = total * (1.0f / 33550336.0f);  // / (N*(N-1)/2)
    }
}

extern "C" void kernel_launch(void* const* d_in, const int* in_sizes, int n_in,
                              void* d_out, int out_size, void* d_ws, size_t ws_size,
                              hipStream_t stream) {
    const float* hidden = (const float*)d_in[0];
    const int* labels = (const int*)d_in[1];
    float* out = (float*)d_out;

    unsigned char* xn = (unsigned char*)d_ws;                          // 2 MB fp8
    float* partials = (float*)((char*)d_ws + (size_t)NROW * DCOL);     // 2080 floats

    normalize_kernel<<<NROW / 4, 256, 0, stream>>>(hidden, xn);
    pairloss_kernel<<<NTILES, 256, 0, stream>>>(xn, labels, partials);
    finalize_kernel<<<1, 512, 0, stream>>>(partials, out);
}